// Round 15
// baseline (50.697 us; speedup 1.0000x reference)
//
#include <hip/hip_runtime.h>
#include <hip/hip_bf16.h>
#include <stdint.h>

typedef __attribute__((ext_vector_type(8))) short bf16x8;
typedef __attribute__((ext_vector_type(4))) float f32x4;

#define LOG2E 1.44269504088896340736f
#define QSCALE (0.25f * LOG2E)

// ---- workspace layout (bytes) ----
#define WS_BIASF 0u          /* 32768: f32 bias in S-MFMA C layout [h][nt][mt][lane][4] */
#define WS_QKVW  32768u      /* 6144: bf16 [96][32], Q rows prescaled */
#define WS_PROJW 38912u      /* 2048: bf16 [32][32] */
#define WS_QKVB  40960u      /* 384: f32 [96], Q prescaled */
#define WS_OUT   41472u      /* 33.5MB: bf16 attn-proj out [8192 win][64 tok][32 co] */
#define NEED_FULL (41472ull + 8192ull*64*32*2)

// ---- per-wave LDS (4096 B): V [2 h][64 m][16 d] stride 32B ----
// O^T blocks overlay V half h after that head's tr16 V reads:
//   block(nt, c4=ln>>2) @ h*2048 + (nt*4+c4)*128, [4 c][16 l]
#define PWAVE 4096

__device__ __forceinline__ uint32_t pk2(float a, float b){
    union{__hip_bfloat162 h;uint32_t u;}c;
    c.h=__float22bfloat162_rn(make_float2(a,b)); return c.u;
}
template<int OFF>
__device__ __forceinline__ uint2 tr16(uint32_t a){
    uint2 d;
    asm volatile("ds_read_b64_tr_b16 %0, %1 offset:%2" : "=v"(d) : "v"(a), "i"(OFF) : "memory");
    return d;
}
__device__ __forceinline__ void lgkm0(){
    asm volatile("s_waitcnt lgkmcnt(0)" ::: "memory");
    __builtin_amdgcn_sched_barrier(0);
}
__device__ __forceinline__ bf16x8 mk8u(uint2 a, uint2 b){
    union{bf16x8 v;uint32_t u[4];}z; z.u[0]=a.x; z.u[1]=a.y; z.u[2]=b.x; z.u[3]=b.y; return z.v;
}
__device__ __forceinline__ bf16x8 mk8q(uint32_t q0, uint32_t q1, uint32_t q2, uint32_t q3){
    union{bf16x8 v;uint32_t u[4];}z; z.u[0]=q0; z.u[1]=q1; z.u[2]=q2; z.u[3]=q3; return z.v;
}
// in-place cross-lane half swaps (gfx950)
__device__ __forceinline__ void pl32(uint32_t &a, uint32_t &b){
    asm volatile("v_permlane32_swap_b32 %0, %1" : "+v"(a), "+v"(b));
}
__device__ __forceinline__ void pl16(uint32_t &a, uint32_t &b){
    asm volatile("v_permlane16_swap_b32 %0, %1" : "+v"(a), "+v"(b));
}
// k=16 MFMA: A/B frag layout = row/col ln, k = 4g..4g+3 (== QKV D-layout per lane)
__device__ __forceinline__ f32x4 mfma16(uint2 a, uint2 b, f32x4 c){
    asm("v_mfma_f32_16x16x16_bf16 %0, %1, %2, %0" : "+v"(c) : "v"(a), "v"(b));
    return c;
}

// ---- one-time prep: f32 bias table [h][nt][mt][lane][4] + bf16 weights + prescaled bias ----
__global__ __launch_bounds__(256) void prep(const float* __restrict__ qkv_w,
                                            const float* __restrict__ qkv_b,
                                            const float* __restrict__ rel_tab,
                                            const float* __restrict__ proj_w,
                                            char* __restrict__ ws)
{
    int t = blockIdx.x*256 + threadIdx.x;   // 0..4095
    if (t < 2048) {                          // biasF: f32x4 per (h, nt, mt, lane)
        int lanei = t & 63, tile = t >> 6;
        int h = tile >> 4, nt = (tile >> 2) & 3, mt = tile & 3;
        int gg = lanei >> 4, lnn = lanei & 15;
        int l = 16*nt + lnn;
        f32x4 v;
        #pragma unroll
        for (int r = 0; r < 4; ++r) {
            int m = 16*mt + 4*gg + r;
            int dr = (l >> 3) - (m >> 3) + 7;
            int dc = (l & 7) - (m & 7) + 7;
            v[r] = rel_tab[(dr*15 + dc)*2 + h] * LOG2E;
        }
        *(f32x4*)(ws + WS_BIASF + (size_t)t*16) = v;
    } else if (t < 3584) {                   // qkv_w -> bf16, Q rows scaled
        int e = (t - 2048) * 2;
        int row = e >> 5;
        float s = (row < 32) ? QSCALE : 1.0f;
        *(uint32_t*)(ws + WS_QKVW + e*2) = pk2(qkv_w[e]*s, qkv_w[e+1]*s);
    } else {                                 // proj_w -> bf16
        int e = (t - 3584) * 2;
        *(uint32_t*)(ws + WS_PROJW + e*2) = pk2(proj_w[e], proj_w[e+1]);
    }
    if (t < 96) {
        float s = (t < 32) ? QSCALE : 1.0f;
        ((float*)(ws + WS_QKVB))[t] = qkv_b[t] * s;
    }
}

// ---- fused per-window kernel: QKV + attention + proj; 2 waves/block, 4KB LDS/wave ----
template<int WSPATH>
__global__ __launch_bounds__(128, 4) void win_attn(
    const float* __restrict__ x, const float* __restrict__ proj_b,
    const char* __restrict__ wsc, uint16_t* __restrict__ wout,
    float* __restrict__ out)
{
    __shared__ __align__(16) char smem_all[2*PWAVE];
    const int tid = threadIdx.x;
    const int wv = tid >> 6, lane = tid & 63;
    const int g = lane >> 4, ln = lane & 15;
    // bijective XCD swizzle (4096 blocks = 8 XCDs x 512)
    const int bid = blockIdx.x;
    const int sb = (bid & 7) * 512 + (bid >> 3);
    const int wid = sb * 2 + wv;
    const int t_i = wid >> 10, wi = (wid >> 5) & 31, wj = wid & 31;
    char* smem = smem_all + wv * PWAVE;
    const uint32_t Lb = (uint32_t)(uintptr_t)(&smem[0]);

    const f32x4* biasF = (const f32x4*)(wsc + WS_BIASF);
    const uint16_t* wbf = (const uint16_t*)(wsc + WS_QKVW);
    const float* qbs = (const float*)(wsc + WS_QKVB);

    // pixel index of tokens ln+16i (reflect-padded)
    int pixb[4];
    #pragma unroll
    for (int i = 0; i < 4; ++i) {
        int tok = 16*i + ln, pr = tok >> 3, pc = tok & 7;
        int ar = wi*4 + pr; if (ar >= 128) ar = 254 - ar;
        int ac = wj*4 + pc; if (ac >= 128) ac = 254 - ac;
        pixb[i] = (t_i*128 + ar)*128 + ac;
    }

    // X B-frags (lane ln -> token col, k = channels 8g..8g+7)
    bf16x8 xf[4];
    #pragma unroll
    for (int nt = 0; nt < 4; ++nt) {
        const float4* p = (const float4*)(x + (size_t)pixb[nt]*32 + 8*g);
        float4 a = p[0], b = p[1];
        union{bf16x8 v; uint32_t u[4];} z;
        z.u[0]=pk2(a.x,a.y); z.u[1]=pk2(a.z,a.w);
        z.u[2]=pk2(b.x,b.y); z.u[3]=pk2(b.z,b.w);
        xf[nt]=z.v;
    }

    // ---- QKV (swapped): D[wrow][tok] = W X^T + b ----
    // Q/K accs -> direct k16 frags in regs (qk[mt][nt], 2 u32 each); V -> LDS
    uint2 qk[4][4];
    #pragma unroll
    for (int mt = 0; mt < 6; ++mt) {
        bf16x8 wf = *(const bf16x8*)(wbf + (ln + 16*mt)*32 + 8*g);
        float4 qb = *(const float4*)(qbs + 16*mt + 4*g);
        #pragma unroll
        for (int nt = 0; nt < 4; ++nt) {
            f32x4 acc = {qb.x, qb.y, qb.z, qb.w};
            acc = __builtin_amdgcn_mfma_f32_16x16x32_bf16(wf, xf[nt], acc, 0, 0, 0);
            if (mt < 4) {            // Q h0,h1 (prescaled in W), K h0,h1
                qk[mt][nt].x = pk2(acc[0], acc[1]);
                qk[mt][nt].y = pk2(acc[2], acc[3]);
            } else {                 // V head mt-4 -> LDS [64 m][16 d]
                int tok = 16*nt + ln;
                uint2 u; u.x = pk2(acc[0], acc[1]); u.y = pk2(acc[2], acc[3]);
                *(uint2*)(smem + (mt-4)*2048 + tok*32 + 8*g) = u;
            }
        }
    }

    const uint32_t one2 = 0x3f803f80u;          // bf16 1.0 pair
    const bf16x8 ones = mk8q(one2, one2, one2, one2);

    // ---- per-head attention; per-nt pipeline ----
    #pragma unroll
    for (int h = 0; h < 2; ++h) {
        // full per-head bias hoist: 16 f32x4 in one independent load burst
        // (static indexing only — fully unrolled below, no scratch)
        f32x4 bp[16];
        #pragma unroll
        for (int t2 = 0; t2 < 16; ++t2)
            bp[t2] = biasF[(h*16 + t2)*64 + lane];

        // V B-frags via hw transpose read
        uint32_t va = Lb + h*2048 + 256*g + 8*ln;
        uint2 v00 = tr16<0>(va),    v01 = tr16<128>(va);
        uint2 v10 = tr16<1024>(va), v11 = tr16<1152>(va);
        lgkm0();
        bf16x8 vb0 = mk8u(v00, v01), vb1 = mk8u(v10, v11);

        #pragma unroll
        for (int nt = 0; nt < 4; ++nt) {
            // S^T tiles (k=16 exact): A=K frag, B=Q frag, C=bias (register-resident)
            __builtin_amdgcn_s_setprio(1);
            f32x4 sc[4];
            #pragma unroll
            for (int mt = 0; mt < 4; ++mt)
                sc[mt] = mfma16(qk[2+h][mt], qk[h][nt], bp[nt*4 + mt]);
            __builtin_amdgcn_s_setprio(0);

            // exp2 (raw v_exp_f32; inputs bounded, no libm expansion)
            #pragma unroll
            for (int mt = 0; mt < 4; ++mt) {
                sc[mt][0]=__builtin_amdgcn_exp2f(sc[mt][0]);
                sc[mt][1]=__builtin_amdgcn_exp2f(sc[mt][1]);
                sc[mt][2]=__builtin_amdgcn_exp2f(sc[mt][2]);
                sc[mt][3]=__builtin_amdgcn_exp2f(sc[mt][3]);
            }

            // pack P UNNORMALIZED and redistribute to PV A-frags in-register
            uint32_t pkA[4], pkB[4];
            #pragma unroll
            for (int mt = 0; mt < 4; ++mt) {
                pkA[mt] = pk2(sc[mt][0], sc[mt][1]);
                pkB[mt] = pk2(sc[mt][2], sc[mt][3]);
            }
            uint32_t a0 = pkA[0], a1 = pkA[1]; pl32(a0, a1); pl16(a0, a1);
            uint32_t b0 = pkB[0], b1 = pkB[1]; pl32(b0, b1); pl16(b0, b1);
            bf16x8 pa0 = mk8q(a0, b0, a1, b1);
            uint32_t a2 = pkA[2], a3 = pkA[3]; pl32(a2, a3); pl16(a2, a3);
            uint32_t b2 = pkB[2], b3 = pkB[3]; pl32(b2, b3); pl16(b2, b3);
            bf16x8 pa1 = mk8q(a2, b2, a3, b3);

            // PV (k=32 over m) + row-sum via ones-MFMA (same D row layout as oc)
            __builtin_amdgcn_s_setprio(1);
            f32x4 z = {0.f,0.f,0.f,0.f};
            z = __builtin_amdgcn_mfma_f32_16x16x32_bf16(pa0, vb0, z, 0, 0, 0);
            f32x4 oc = __builtin_amdgcn_mfma_f32_16x16x32_bf16(pa1, vb1, z, 0, 0, 0);
            f32x4 sm = {0.f,0.f,0.f,0.f};
            sm = __builtin_amdgcn_mfma_f32_16x16x32_bf16(pa0, ones, sm, 0, 0, 0);
            sm = __builtin_amdgcn_mfma_f32_16x16x32_bf16(pa1, ones, sm, 0, 0, 0);
            __builtin_amdgcn_s_setprio(0);

            // normalize post-PV (raw v_rcp_f32)
            oc[0] *= __builtin_amdgcn_rcpf(sm[0]);
            oc[1] *= __builtin_amdgcn_rcpf(sm[1]);
            oc[2] *= __builtin_amdgcn_rcpf(sm[2]);
            oc[3] *= __builtin_amdgcn_rcpf(sm[3]);

            // O^T store overlaying V half h (dead after tr16 above)
            uint2 u; u.x = pk2(oc[0], oc[1]); u.y = pk2(oc[2], oc[3]);
            *(uint2*)(smem + h*2048 + (nt*4 + (ln>>2))*128 + (ln&3)*32 + 8*g) = u;
        }
    }

    // ---- proj (swapped): out^T = mfma(W2, O^T) ----
    const uint16_t* pwbf = (const uint16_t*)(wsc + WS_PROJW);
    bf16x8 w2f[2];
    w2f[0] = *(const bf16x8*)(pwbf + ln*32 + 8*g);
    w2f[1] = *(const bf16x8*)(pwbf + (16 + ln)*32 + 8*g);
    float4 pbv[2];
    pbv[0] = *(const float4*)(proj_b + 4*g);
    pbv[1] = *(const float4*)(proj_b + 16 + 4*g);

    uint32_t ob = Lb + ((uint32_t)(g >> 1) << 11) + ((uint32_t)(g & 1) << 8) + 8*ln;
    uint2 a0=tr16<0>(ob),    a1=tr16<128>(ob);
    uint2 b0=tr16<512>(ob),  b1=tr16<640>(ob);
    uint2 c0=tr16<1024>(ob), c1=tr16<1152>(ob);
    uint2 d0=tr16<1536>(ob), d1=tr16<1664>(ob);
    lgkm0();
    bf16x8 oa[4];
    oa[0]=mk8u(a0,a1); oa[1]=mk8u(b0,b1); oa[2]=mk8u(c0,c1); oa[3]=mk8u(d0,d1);

    #pragma unroll
    for (int mt2 = 0; mt2 < 2; ++mt2) {
        #pragma unroll
        for (int nt = 0; nt < 4; ++nt) {
            f32x4 acc = {pbv[mt2].x, pbv[mt2].y, pbv[mt2].z, pbv[mt2].w};
            acc = __builtin_amdgcn_mfma_f32_16x16x32_bf16(w2f[mt2], oa[nt], acc, 0, 0, 0);
            if (WSPATH) {   // wout[win][l=16nt+ln][co=16mt2+4g+0..3], packed
                uint2 u; u.x = pk2(acc[0], acc[1]); u.y = pk2(acc[2], acc[3]);
                *(uint2*)(wout + ((size_t)wid*64 + 16*nt + ln)*32 + 16*mt2 + 4*g) = u;
            } else {
                #pragma unroll
                for (int r = 0; r < 4; ++r)
                    atomicAdd(out + (size_t)pixb[nt]*32 + 16*mt2 + 4*g + r, acc[r]);
            }
        }
    }
}

// gather <=3x3 contributing windows per output pixel, divide by count
__global__ __launch_bounds__(256) void gather_out(const uint16_t* __restrict__ ws,
                                                  float* __restrict__ out)
{
    int gid = blockIdx.x * 256 + threadIdx.x;   // pixels * 8 float4s
    int q = gid & 7;
    int c = (gid >> 3) & 127;
    int r = (gid >> 10) & 127;
    int t = gid >> 17;

    int wr[3], pr[3], nr = 0;
    { int w0 = r >> 2;
      wr[0] = w0; pr[0] = r & 3; nr = 1;
      if (w0 >= 1) { wr[nr] = w0 - 1; pr[nr] = (r & 3) + 4; nr++; }
      if (r >= 123 && r <= 126) { wr[nr] = 31; pr[nr] = 130 - r; nr++; } }
    int wc[3], pc[3], nc = 0;
    { int w0 = c >> 2;
      wc[0] = w0; pc[0] = c & 3; nc = 1;
      if (w0 >= 1) { wc[nc] = w0 - 1; pc[nc] = (c & 3) + 4; nc++; }
      if (c >= 123 && c <= 126) { wc[nc] = 31; pc[nc] = 130 - c; nc++; } }

    float4 acc; acc.x = acc.y = acc.z = acc.w = 0.f;
    #pragma unroll
    for (int i = 0; i < 3; ++i) {
        #pragma unroll
        for (int j = 0; j < 3; ++j) {
            if (i < nr && j < nc) {
                int win = t*1024 + wr[i]*32 + wc[j];
                int tok = pr[i]*8 + pc[j];
                ushort4 v = *reinterpret_cast<const ushort4*>(ws + ((size_t)win*64 + tok)*32 + q*4);
                union { uint32_t u; float f; } a0,a1,a2,a3;
                a0.u = (uint32_t)v.x << 16; a1.u = (uint32_t)v.y << 16;
                a2.u = (uint32_t)v.z << 16; a3.u = (uint32_t)v.w << 16;
                acc.x += a0.f; acc.y += a1.f; acc.z += a2.f; acc.w += a3.f;
            }
        }
    }
    float inv = __builtin_amdgcn_rcpf((float)(nr*nc));
    acc.x *= inv; acc.y *= inv; acc.z *= inv; acc.w *= inv;
    reinterpret_cast<float4*>(out)[gid] = acc;
}

// fallback normalize (atomic path)
__global__ __launch_bounds__(256) void div_kernel(float* __restrict__ out)
{
    int gid = blockIdx.x*blockDim.x + threadIdx.x;
    const int total4 = 8*128*128*32/4;
    if (gid >= total4) return;
    int pix = gid >> 3;
    int c_ = pix % 128;
    int r_ = (pix / 128) % 128;
    int cr = 0, cc = 0;
    for (int i = 0; i < 32; ++i) {
        #pragma unroll
        for (int p = 0; p < 8; ++p) {
            int rr = i*4 + p; if (rr >= 128) rr = 254 - rr;
            cr += (rr == r_);
            int aa = i*4 + p; if (aa >= 128) aa = 254 - aa;
            cc += (aa == c_);
        }
    }
    float inv = 1.f / ((float)cr*(float)cc + 1e-10f);
    float4* p4 = reinterpret_cast<float4*>(out) + gid;
    float4 v = *p4;
    v.x *= inv; v.y *= inv; v.z *= inv; v.w *= inv;
    *p4 = v;
}

extern "C" void kernel_launch(void* const* d_in, const int* in_sizes, int n_in,
                              void* d_out, int out_size, void* d_ws, size_t ws_size,
                              hipStream_t stream) {
    const float* x       = (const float*)d_in[0];
    const float* qkv_w   = (const float*)d_in[1];
    const float* qkv_b   = (const float*)d_in[2];
    const float* rel_tab = (const float*)d_in[3];
    const float* proj_w  = (const float*)d_in[4];
    const float* proj_b  = (const float*)d_in[5];
    float* out = (float*)d_out;
    char* ws = (char*)d_ws;

    prep<<<16, 256, 0, stream>>>(qkv_w, qkv_b, rel_tab, proj_w, ws);

    if (ws_size >= NEED_FULL) {
        win_attn<1><<<4096, 128, 0, stream>>>(x, proj_b, (const char*)ws,
                                              (uint16_t*)(ws + WS_OUT), out);
        gather_out<<<4096, 256, 0, stream>>>((const uint16_t*)(ws + WS_OUT), out);
    } else {
        hipMemsetAsync(out, 0, (size_t)out_size*sizeof(float), stream);
        win_attn<0><<<4096, 128, 0, stream>>>(x, proj_b, (const char*)ws, nullptr, out);
        const int tot4 = 8*128*128*32/4;
        div_kernel<<<(tot4 + 255)/256, 256, 0, stream>>>(out);
    }
}

// Round 16
// 49.791 us; speedup vs baseline: 1.0182x; 1.0182x over previous
//
#include <hip/hip_runtime.h>
#include <hip/hip_bf16.h>
#include <stdint.h>

typedef __attribute__((ext_vector_type(8))) short bf16x8;
typedef __attribute__((ext_vector_type(4))) float f32x4;

#define LOG2E 1.44269504088896340736f
#define QSCALE (0.25f * LOG2E)

// ---- workspace layout (bytes) ----
#define WS_BIASF 0u          /* 32768: f32 bias in S-MFMA C layout [h][nt][mt][lane][4] */
#define WS_QKVW  32768u      /* 6144: bf16 [96][32], Q rows prescaled */
#define WS_PROJW 38912u      /* 2048: bf16 [32][32] */
#define WS_QKVB  40960u      /* 384: f32 [96], Q prescaled */
#define WS_OUT   41472u      /* 33.5MB: bf16 attn-proj out [8192 win][64 tok][32 co] */
#define NEED_FULL (41472ull + 8192ull*64*32*2)

// ---- per-wave LDS (4096 B): V [2 h][64 m][16 d] stride 32B ----
// O^T blocks overlay V half h after that head's tr16 V reads:
//   block(nt, c4=ln>>2) @ h*2048 + (nt*4+c4)*128, [4 c][16 l]
#define PWAVE 4096

__device__ __forceinline__ uint32_t pk2(float a, float b){
    union{__hip_bfloat162 h;uint32_t u;}c;
    c.h=__float22bfloat162_rn(make_float2(a,b)); return c.u;
}
template<int OFF>
__device__ __forceinline__ uint2 tr16(uint32_t a){
    uint2 d;
    asm volatile("ds_read_b64_tr_b16 %0, %1 offset:%2" : "=v"(d) : "v"(a), "i"(OFF) : "memory");
    return d;
}
__device__ __forceinline__ void lgkm0(){
    asm volatile("s_waitcnt lgkmcnt(0)" ::: "memory");
    __builtin_amdgcn_sched_barrier(0);
}
__device__ __forceinline__ bf16x8 mk8u(uint2 a, uint2 b){
    union{bf16x8 v;uint32_t u[4];}z; z.u[0]=a.x; z.u[1]=a.y; z.u[2]=b.x; z.u[3]=b.y; return z.v;
}
__device__ __forceinline__ bf16x8 mk8q(uint32_t q0, uint32_t q1, uint32_t q2, uint32_t q3){
    union{bf16x8 v;uint32_t u[4];}z; z.u[0]=q0; z.u[1]=q1; z.u[2]=q2; z.u[3]=q3; return z.v;
}
// in-place cross-lane half swaps (gfx950)
__device__ __forceinline__ void pl32(uint32_t &a, uint32_t &b){
    asm volatile("v_permlane32_swap_b32 %0, %1" : "+v"(a), "+v"(b));
}
__device__ __forceinline__ void pl16(uint32_t &a, uint32_t &b){
    asm volatile("v_permlane16_swap_b32 %0, %1" : "+v"(a), "+v"(b));
}
// k=16 MFMA: A/B frag layout = row/col ln, k = 4g..4g+3 (== QKV D-layout per lane)
__device__ __forceinline__ f32x4 mfma16(uint2 a, uint2 b, f32x4 c){
    asm("v_mfma_f32_16x16x16_bf16 %0, %1, %2, %0" : "+v"(c) : "v"(a), "v"(b));
    return c;
}

// ---- one-time prep: f32 bias table [h][nt][mt][lane][4] + bf16 weights + prescaled bias ----
__global__ __launch_bounds__(256) void prep(const float* __restrict__ qkv_w,
                                            const float* __restrict__ qkv_b,
                                            const float* __restrict__ rel_tab,
                                            const float* __restrict__ proj_w,
                                            char* __restrict__ ws)
{
    int t = blockIdx.x*256 + threadIdx.x;   // 0..4095
    if (t < 2048) {                          // biasF: f32x4 per (h, nt, mt, lane)
        int lanei = t & 63, tile = t >> 6;
        int h = tile >> 4, nt = (tile >> 2) & 3, mt = tile & 3;
        int gg = lanei >> 4, lnn = lanei & 15;
        int l = 16*nt + lnn;
        f32x4 v;
        #pragma unroll
        for (int r = 0; r < 4; ++r) {
            int m = 16*mt + 4*gg + r;
            int dr = (l >> 3) - (m >> 3) + 7;
            int dc = (l & 7) - (m & 7) + 7;
            v[r] = rel_tab[(dr*15 + dc)*2 + h] * LOG2E;
        }
        *(f32x4*)(ws + WS_BIASF + (size_t)t*16) = v;
    } else if (t < 3584) {                   // qkv_w -> bf16, Q rows scaled
        int e = (t - 2048) * 2;
        int row = e >> 5;
        float s = (row < 32) ? QSCALE : 1.0f;
        *(uint32_t*)(ws + WS_QKVW + e*2) = pk2(qkv_w[e]*s, qkv_w[e+1]*s);
    } else {                                 // proj_w -> bf16
        int e = (t - 3584) * 2;
        *(uint32_t*)(ws + WS_PROJW + e*2) = pk2(proj_w[e], proj_w[e+1]);
    }
    if (t < 96) {
        float s = (t < 32) ? QSCALE : 1.0f;
        ((float*)(ws + WS_QKVB))[t] = qkv_b[t] * s;
    }
}

// ---- fused per-window kernel: QKV + attention + proj; 2 waves/block, 4KB LDS/wave ----
template<int WSPATH>
__global__ __launch_bounds__(128, 4) void win_attn(
    const float* __restrict__ x, const float* __restrict__ proj_b,
    const char* __restrict__ wsc, uint16_t* __restrict__ wout,
    float* __restrict__ out)
{
    __shared__ __align__(16) char smem_all[2*PWAVE];
    const int tid = threadIdx.x;
    const int wv = tid >> 6, lane = tid & 63;
    const int g = lane >> 4, ln = lane & 15;
    // bijective XCD swizzle (4096 blocks = 8 XCDs x 512): XCD x owns frame t_i = x
    const int bid = blockIdx.x;
    const int sb = (bid & 7) * 512 + (bid >> 3);
    const int wid = sb * 2 + wv;
    const int t_i = wid >> 10, wi = (wid >> 5) & 31, wj = wid & 31;
    char* smem = smem_all + wv * PWAVE;
    const uint32_t Lb = (uint32_t)(uintptr_t)(&smem[0]);

    const f32x4* biasF = (const f32x4*)(wsc + WS_BIASF);
    const uint16_t* wbf = (const uint16_t*)(wsc + WS_QKVW);
    const float* qbs = (const float*)(wsc + WS_QKVB);

    // pixel index of tokens ln+16i (reflect-padded)
    int pixb[4];
    #pragma unroll
    for (int i = 0; i < 4; ++i) {
        int tok = 16*i + ln, pr = tok >> 3, pc = tok & 7;
        int ar = wi*4 + pr; if (ar >= 128) ar = 254 - ar;
        int ac = wj*4 + pc; if (ac >= 128) ac = 254 - ac;
        pixb[i] = (t_i*128 + ar)*128 + ac;
    }

    // X B-frags (lane ln -> token col, k = channels 8g..8g+7)
    bf16x8 xf[4];
    #pragma unroll
    for (int nt = 0; nt < 4; ++nt) {
        const float4* p = (const float4*)(x + (size_t)pixb[nt]*32 + 8*g);
        float4 a = p[0], b = p[1];
        union{bf16x8 v; uint32_t u[4];} z;
        z.u[0]=pk2(a.x,a.y); z.u[1]=pk2(a.z,a.w);
        z.u[2]=pk2(b.x,b.y); z.u[3]=pk2(b.z,b.w);
        xf[nt]=z.v;
    }

    // ---- QKV (swapped): D[wrow][tok] = W X^T + b ----
    // Q/K accs -> direct k16 frags in regs (qk[mt][nt], 2 u32 each); V -> LDS
    uint2 qk[4][4];
    #pragma unroll
    for (int mt = 0; mt < 6; ++mt) {
        bf16x8 wf = *(const bf16x8*)(wbf + (ln + 16*mt)*32 + 8*g);
        float4 qb = *(const float4*)(qbs + 16*mt + 4*g);
        #pragma unroll
        for (int nt = 0; nt < 4; ++nt) {
            f32x4 acc = {qb.x, qb.y, qb.z, qb.w};
            acc = __builtin_amdgcn_mfma_f32_16x16x32_bf16(wf, xf[nt], acc, 0, 0, 0);
            if (mt < 4) {            // Q h0,h1 (prescaled in W), K h0,h1
                qk[mt][nt].x = pk2(acc[0], acc[1]);
                qk[mt][nt].y = pk2(acc[2], acc[3]);
            } else {                 // V head mt-4 -> LDS [64 m][16 d]
                int tok = 16*nt + ln;
                uint2 u; u.x = pk2(acc[0], acc[1]); u.y = pk2(acc[2], acc[3]);
                *(uint2*)(smem + (mt-4)*2048 + tok*32 + 8*g) = u;
            }
        }
    }

    const uint32_t one2 = 0x3f803f80u;          // bf16 1.0 pair
    const bf16x8 ones = mk8q(one2, one2, one2, one2);

    // ---- per-head attention; per-nt pipeline ----
    #pragma unroll
    for (int h = 0; h < 2; ++h) {
        // V B-frags via hw transpose read
        uint32_t va = Lb + h*2048 + 256*g + 8*ln;
        uint2 v00 = tr16<0>(va),    v01 = tr16<128>(va);
        uint2 v10 = tr16<1024>(va), v11 = tr16<1152>(va);
        lgkm0();
        bf16x8 vb0 = mk8u(v00, v01), vb1 = mk8u(v10, v11);

        f32x4 bpc[4];
        #pragma unroll
        for (int mt = 0; mt < 4; ++mt)
            bpc[mt] = biasF[((h*4 + 0)*4 + mt)*64 + lane];

        #pragma unroll
        for (int nt = 0; nt < 4; ++nt) {
            // prefetch next nt's bias while computing
            f32x4 bpn[4];
            const int ntn = (nt < 3) ? nt + 1 : 3;
            #pragma unroll
            for (int mt = 0; mt < 4; ++mt)
                bpn[mt] = biasF[((h*4 + ntn)*4 + mt)*64 + lane];

            // S^T tiles (k=16 exact): A=K frag, B=Q frag, C=bias (f32 direct)
            __builtin_amdgcn_s_setprio(1);
            f32x4 sc[4];
            #pragma unroll
            for (int mt = 0; mt < 4; ++mt)
                sc[mt] = mfma16(qk[2+h][mt], qk[h][nt], bpc[mt]);
            __builtin_amdgcn_s_setprio(0);

            // exp2 (raw v_exp_f32; inputs bounded, no libm expansion)
            #pragma unroll
            for (int mt = 0; mt < 4; ++mt) {
                sc[mt][0]=__builtin_amdgcn_exp2f(sc[mt][0]);
                sc[mt][1]=__builtin_amdgcn_exp2f(sc[mt][1]);
                sc[mt][2]=__builtin_amdgcn_exp2f(sc[mt][2]);
                sc[mt][3]=__builtin_amdgcn_exp2f(sc[mt][3]);
            }

            // pack P UNNORMALIZED and redistribute to PV A-frags in-register
            uint32_t pkA[4], pkB[4];
            #pragma unroll
            for (int mt = 0; mt < 4; ++mt) {
                pkA[mt] = pk2(sc[mt][0], sc[mt][1]);
                pkB[mt] = pk2(sc[mt][2], sc[mt][3]);
            }
            uint32_t a0 = pkA[0], a1 = pkA[1]; pl32(a0, a1); pl16(a0, a1);
            uint32_t b0 = pkB[0], b1 = pkB[1]; pl32(b0, b1); pl16(b0, b1);
            bf16x8 pa0 = mk8q(a0, b0, a1, b1);
            uint32_t a2 = pkA[2], a3 = pkA[3]; pl32(a2, a3); pl16(a2, a3);
            uint32_t b2 = pkB[2], b3 = pkB[3]; pl32(b2, b3); pl16(b2, b3);
            bf16x8 pa1 = mk8q(a2, b2, a3, b3);

            // PV (k=32 over m) + row-sum via ones-MFMA (same D row layout as oc)
            __builtin_amdgcn_s_setprio(1);
            f32x4 z = {0.f,0.f,0.f,0.f};
            z = __builtin_amdgcn_mfma_f32_16x16x32_bf16(pa0, vb0, z, 0, 0, 0);
            f32x4 oc = __builtin_amdgcn_mfma_f32_16x16x32_bf16(pa1, vb1, z, 0, 0, 0);
            f32x4 sm = {0.f,0.f,0.f,0.f};
            sm = __builtin_amdgcn_mfma_f32_16x16x32_bf16(pa0, ones, sm, 0, 0, 0);
            sm = __builtin_amdgcn_mfma_f32_16x16x32_bf16(pa1, ones, sm, 0, 0, 0);
            __builtin_amdgcn_s_setprio(0);

            // normalize post-PV (raw v_rcp_f32)
            oc[0] *= __builtin_amdgcn_rcpf(sm[0]);
            oc[1] *= __builtin_amdgcn_rcpf(sm[1]);
            oc[2] *= __builtin_amdgcn_rcpf(sm[2]);
            oc[3] *= __builtin_amdgcn_rcpf(sm[3]);

            // O^T store overlaying V half h (dead after tr16 above)
            uint2 u; u.x = pk2(oc[0], oc[1]); u.y = pk2(oc[2], oc[3]);
            *(uint2*)(smem + h*2048 + (nt*4 + (ln>>2))*128 + (ln&3)*32 + 8*g) = u;

            #pragma unroll
            for (int mt = 0; mt < 4; ++mt) bpc[mt] = bpn[mt];
        }
    }

    // ---- proj (swapped): out^T = mfma(W2, O^T) ----
    const uint16_t* pwbf = (const uint16_t*)(wsc + WS_PROJW);
    bf16x8 w2f[2];
    w2f[0] = *(const bf16x8*)(pwbf + ln*32 + 8*g);
    w2f[1] = *(const bf16x8*)(pwbf + (16 + ln)*32 + 8*g);
    float4 pbv[2];
    pbv[0] = *(const float4*)(proj_b + 4*g);
    pbv[1] = *(const float4*)(proj_b + 16 + 4*g);

    uint32_t ob = Lb + ((uint32_t)(g >> 1) << 11) + ((uint32_t)(g & 1) << 8) + 8*ln;
    uint2 a0=tr16<0>(ob),    a1=tr16<128>(ob);
    uint2 b0=tr16<512>(ob),  b1=tr16<640>(ob);
    uint2 c0=tr16<1024>(ob), c1=tr16<1152>(ob);
    uint2 d0=tr16<1536>(ob), d1=tr16<1664>(ob);
    lgkm0();
    bf16x8 oa[4];
    oa[0]=mk8u(a0,a1); oa[1]=mk8u(b0,b1); oa[2]=mk8u(c0,c1); oa[3]=mk8u(d0,d1);

    #pragma unroll
    for (int mt2 = 0; mt2 < 2; ++mt2) {
        #pragma unroll
        for (int nt = 0; nt < 4; ++nt) {
            f32x4 acc = {pbv[mt2].x, pbv[mt2].y, pbv[mt2].z, pbv[mt2].w};
            acc = __builtin_amdgcn_mfma_f32_16x16x32_bf16(w2f[mt2], oa[nt], acc, 0, 0, 0);
            if (WSPATH) {   // wout[win][l=16nt+ln][co=16mt2+4g+0..3], packed
                uint2 u; u.x = pk2(acc[0], acc[1]); u.y = pk2(acc[2], acc[3]);
                *(uint2*)(wout + ((size_t)wid*64 + 16*nt + ln)*32 + 16*mt2 + 4*g) = u;
            } else {
                #pragma unroll
                for (int r = 0; r < 4; ++r)
                    atomicAdd(out + (size_t)pixb[nt]*32 + 16*mt2 + 4*g + r, acc[r]);
            }
        }
    }
}

// gather <=3x3 contributing windows per output pixel, divide by count.
// Block index remapped so block b serves FRAME (b&7) and lands on XCD (b&7) —
// the same XCD whose L2 holds that frame's wout slice (win_attn swizzle). Bijective.
__global__ __launch_bounds__(256) void gather_out(const uint16_t* __restrict__ ws,
                                                  float* __restrict__ out)
{
    const int b = blockIdx.x;
    int gid = ((b & 7) << 17) + ((b >> 3) << 8) + threadIdx.x;   // pixels * 8 float4s
    int q = gid & 7;
    int c = (gid >> 3) & 127;
    int r = (gid >> 10) & 127;
    int t = gid >> 17;

    int wr[3], pr[3], nr = 0;
    { int w0 = r >> 2;
      wr[0] = w0; pr[0] = r & 3; nr = 1;
      if (w0 >= 1) { wr[nr] = w0 - 1; pr[nr] = (r & 3) + 4; nr++; }
      if (r >= 123 && r <= 126) { wr[nr] = 31; pr[nr] = 130 - r; nr++; } }
    int wc[3], pc[3], nc = 0;
    { int w0 = c >> 2;
      wc[0] = w0; pc[0] = c & 3; nc = 1;
      if (w0 >= 1) { wc[nc] = w0 - 1; pc[nc] = (c & 3) + 4; nc++; }
      if (c >= 123 && c <= 126) { wc[nc] = 31; pc[nc] = 130 - c; nc++; } }

    float4 acc; acc.x = acc.y = acc.z = acc.w = 0.f;
    #pragma unroll
    for (int i = 0; i < 3; ++i) {
        #pragma unroll
        for (int j = 0; j < 3; ++j) {
            if (i < nr && j < nc) {
                int win = t*1024 + wr[i]*32 + wc[j];
                int tok = pr[i]*8 + pc[j];
                ushort4 v = *reinterpret_cast<const ushort4*>(ws + ((size_t)win*64 + tok)*32 + q*4);
                union { uint32_t u; float f; } a0,a1,a2,a3;
                a0.u = (uint32_t)v.x << 16; a1.u = (uint32_t)v.y << 16;
                a2.u = (uint32_t)v.z << 16; a3.u = (uint32_t)v.w << 16;
                acc.x += a0.f; acc.y += a1.f; acc.z += a2.f; acc.w += a3.f;
            }
        }
    }
    float inv = __builtin_amdgcn_rcpf((float)(nr*nc));
    acc.x *= inv; acc.y *= inv; acc.z *= inv; acc.w *= inv;
    reinterpret_cast<float4*>(out)[gid] = acc;
}

// fallback normalize (atomic path)
__global__ __launch_bounds__(256) void div_kernel(float* __restrict__ out)
{
    int gid = blockIdx.x*blockDim.x + threadIdx.x;
    const int total4 = 8*128*128*32/4;
    if (gid >= total4) return;
    int pix = gid >> 3;
    int c_ = pix % 128;
    int r_ = (pix / 128) % 128;
    int cr = 0, cc = 0;
    for (int i = 0; i < 32; ++i) {
        #pragma unroll
        for (int p = 0; p < 8; ++p) {
            int rr = i*4 + p; if (rr >= 128) rr = 254 - rr;
            cr += (rr == r_);
            int aa = i*4 + p; if (aa >= 128) aa = 254 - aa;
            cc += (aa == c_);
        }
    }
    float inv = 1.f / ((float)cr*(float)cc + 1e-10f);
    float4* p4 = reinterpret_cast<float4*>(out) + gid;
    float4 v = *p4;
    v.x *= inv; v.y *= inv; v.z *= inv; v.w *= inv;
    *p4 = v;
}

extern "C" void kernel_launch(void* const* d_in, const int* in_sizes, int n_in,
                              void* d_out, int out_size, void* d_ws, size_t ws_size,
                              hipStream_t stream) {
    const float* x       = (const float*)d_in[0];
    const float* qkv_w   = (const float*)d_in[1];
    const float* qkv_b   = (const float*)d_in[2];
    const float* rel_tab = (const float*)d_in[3];
    const float* proj_w  = (const float*)d_in[4];
    const float* proj_b  = (const float*)d_in[5];
    float* out = (float*)d_out;
    char* ws = (char*)d_ws;

    prep<<<16, 256, 0, stream>>>(qkv_w, qkv_b, rel_tab, proj_w, ws);

    if (ws_size >= NEED_FULL) {
        win_attn<1><<<4096, 128, 0, stream>>>(x, proj_b, (const char*)ws,
                                              (uint16_t*)(ws + WS_OUT), out);
        gather_out<<<4096, 256, 0, stream>>>((const uint16_t*)(ws + WS_OUT), out);
    } else {
        hipMemsetAsync(out, 0, (size_t)out_size*sizeof(float), stream);
        win_attn<0><<<4096, 128, 0, stream>>>(x, proj_b, (const char*)ws, nullptr, out);
        const int tot4 = 8*128*128*32/4;
        div_kernel<<<(tot4 + 255)/256, 256, 0, stream>>>(out);
    }
}

// Round 18
// 49.580 us; speedup vs baseline: 1.0225x; 1.0043x over previous
//
#include <hip/hip_runtime.h>
#include <hip/hip_bf16.h>
#include <stdint.h>

typedef __attribute__((ext_vector_type(8))) short bf16x8;
typedef __attribute__((ext_vector_type(4))) float f32x4;

#define LOG2E 1.44269504088896340736f
#define QSCALE (0.25f * LOG2E)

// ---- workspace layout (bytes) ----
#define WS_BIASF 0u          /* 32768: f32 bias in S-MFMA C layout [h][nt][mt][lane][4] */
#define WS_QKVW  32768u      /* 6144: bf16 [96][32], Q rows prescaled */
#define WS_PROJW 38912u      /* 2048: bf16 [32][32] */
#define WS_QKVB  40960u      /* 384: f32 [96], Q prescaled */
#define WS_OUT   41472u      /* 33.5MB: bf16 attn-proj out [8192 win][64 tok][32 co] */
#define NEED_FULL (41472ull + 8192ull*64*32*2)

// ---- per-wave LDS (4096 B): V [2 h][64 m][16 d] stride 32B ----
// O^T blocks overlay V half h after that head's tr16 V reads:
//   block(nt, c4=ln>>2) @ h*2048 + (nt*4+c4)*128, [4 c][16 l]
#define PWAVE 4096

__device__ __forceinline__ uint32_t pk2(float a, float b){
    union{__hip_bfloat162 h;uint32_t u;}c;
    c.h=__float22bfloat162_rn(make_float2(a,b)); return c.u;
}
template<int OFF>
__device__ __forceinline__ uint2 tr16(uint32_t a){
    uint2 d;
    asm volatile("ds_read_b64_tr_b16 %0, %1 offset:%2" : "=v"(d) : "v"(a), "i"(OFF) : "memory");
    return d;
}
__device__ __forceinline__ void lgkm0(){
    asm volatile("s_waitcnt lgkmcnt(0)" ::: "memory");
    __builtin_amdgcn_sched_barrier(0);
}
__device__ __forceinline__ bf16x8 mk8u(uint2 a, uint2 b){
    union{bf16x8 v;uint32_t u[4];}z; z.u[0]=a.x; z.u[1]=a.y; z.u[2]=b.x; z.u[3]=b.y; return z.v;
}
__device__ __forceinline__ bf16x8 mk8q(uint32_t q0, uint32_t q1, uint32_t q2, uint32_t q3){
    union{bf16x8 v;uint32_t u[4];}z; z.u[0]=q0; z.u[1]=q1; z.u[2]=q2; z.u[3]=q3; return z.v;
}
// in-place cross-lane half swaps (gfx950)
__device__ __forceinline__ void pl32(uint32_t &a, uint32_t &b){
    asm volatile("v_permlane32_swap_b32 %0, %1" : "+v"(a), "+v"(b));
}
__device__ __forceinline__ void pl16(uint32_t &a, uint32_t &b){
    asm volatile("v_permlane16_swap_b32 %0, %1" : "+v"(a), "+v"(b));
}
// k=16 MFMA: A/B frag layout = row/col ln, k = 4g..4g+3 (== QKV D-layout per lane)
__device__ __forceinline__ f32x4 mfma16(uint2 a, uint2 b, f32x4 c){
    asm("v_mfma_f32_16x16x16_bf16 %0, %1, %2, %0" : "+v"(c) : "v"(a), "v"(b));
    return c;
}

// ---- one-time prep: f32 bias table [h][nt][mt][lane][4] + bf16 weights + prescaled bias ----
__global__ __launch_bounds__(256) void prep(const float* __restrict__ qkv_w,
                                            const float* __restrict__ qkv_b,
                                            const float* __restrict__ rel_tab,
                                            const float* __restrict__ proj_w,
                                            char* __restrict__ ws)
{
    int t = blockIdx.x*256 + threadIdx.x;   // 0..4095
    if (t < 2048) {                          // biasF: f32x4 per (h, nt, mt, lane)
        int lanei = t & 63, tile = t >> 6;
        int h = tile >> 4, nt = (tile >> 2) & 3, mt = tile & 3;
        int gg = lanei >> 4, lnn = lanei & 15;
        int l = 16*nt + lnn;
        f32x4 v;
        #pragma unroll
        for (int r = 0; r < 4; ++r) {
            int m = 16*mt + 4*gg + r;
            int dr = (l >> 3) - (m >> 3) + 7;
            int dc = (l & 7) - (m & 7) + 7;
            v[r] = rel_tab[(dr*15 + dc)*2 + h] * LOG2E;
        }
        *(f32x4*)(ws + WS_BIASF + (size_t)t*16) = v;
    } else if (t < 3584) {                   // qkv_w -> bf16, Q rows scaled
        int e = (t - 2048) * 2;
        int row = e >> 5;
        float s = (row < 32) ? QSCALE : 1.0f;
        *(uint32_t*)(ws + WS_QKVW + e*2) = pk2(qkv_w[e]*s, qkv_w[e+1]*s);
    } else {                                 // proj_w -> bf16
        int e = (t - 3584) * 2;
        *(uint32_t*)(ws + WS_PROJW + e*2) = pk2(proj_w[e], proj_w[e+1]);
    }
    if (t < 96) {
        float s = (t < 32) ? QSCALE : 1.0f;
        ((float*)(ws + WS_QKVB))[t] = qkv_b[t] * s;
    }
}

// ---- fused per-window kernel: QKV + attention + proj; 2 waves/block, 4KB LDS/wave ----
template<int WSPATH>
__global__ __launch_bounds__(128, 4) void win_attn(
    const float* __restrict__ x, const float* __restrict__ proj_b,
    const char* __restrict__ wsc, uint16_t* __restrict__ wout,
    float* __restrict__ out)
{
    __shared__ __align__(16) char smem_all[2*PWAVE];
    const int tid = threadIdx.x;
    const int wv = tid >> 6, lane = tid & 63;
    const int g = lane >> 4, ln = lane & 15;
    // bijective XCD swizzle (4096 blocks = 8 XCDs x 512): XCD x owns frame t_i = x
    const int bid = blockIdx.x;
    const int sb = (bid & 7) * 512 + (bid >> 3);
    const int wid = sb * 2 + wv;
    const int t_i = wid >> 10, wi = (wid >> 5) & 31, wj = wid & 31;
    char* smem = smem_all + wv * PWAVE;
    const uint32_t Lb = (uint32_t)(uintptr_t)(&smem[0]);

    const f32x4* biasF = (const f32x4*)(wsc + WS_BIASF);
    const uint16_t* wbf = (const uint16_t*)(wsc + WS_QKVW);
    const float* qbs = (const float*)(wsc + WS_QKVB);

    // pixel index of tokens ln+16i (reflect-padded)
    int pixb[4];
    #pragma unroll
    for (int i = 0; i < 4; ++i) {
        int tok = 16*i + ln, pr = tok >> 3, pc = tok & 7;
        int ar = wi*4 + pr; if (ar >= 128) ar = 254 - ar;
        int ac = wj*4 + pc; if (ac >= 128) ac = 254 - ac;
        pixb[i] = (t_i*128 + ar)*128 + ac;
    }

    // X B-frags (lane ln -> token col, k = channels 8g..8g+7)
    bf16x8 xf[4];
    #pragma unroll
    for (int nt = 0; nt < 4; ++nt) {
        const float4* p = (const float4*)(x + (size_t)pixb[nt]*32 + 8*g);
        float4 a = p[0], b = p[1];
        union{bf16x8 v; uint32_t u[4];} z;
        z.u[0]=pk2(a.x,a.y); z.u[1]=pk2(a.z,a.w);
        z.u[2]=pk2(b.x,b.y); z.u[3]=pk2(b.z,b.w);
        xf[nt]=z.v;
    }

    // ---- QKV (swapped): D[wrow][tok] = W X^T + b ----
    // Q/K accs -> direct k16 frags in regs (qk[mt][nt], 2 u32 each); V -> LDS
    uint2 qk[4][4];
    #pragma unroll
    for (int mt = 0; mt < 6; ++mt) {
        bf16x8 wf = *(const bf16x8*)(wbf + (ln + 16*mt)*32 + 8*g);
        float4 qb = *(const float4*)(qbs + 16*mt + 4*g);
        #pragma unroll
        for (int nt = 0; nt < 4; ++nt) {
            f32x4 acc = {qb.x, qb.y, qb.z, qb.w};
            acc = __builtin_amdgcn_mfma_f32_16x16x32_bf16(wf, xf[nt], acc, 0, 0, 0);
            if (mt < 4) {            // Q h0,h1 (prescaled in W), K h0,h1
                qk[mt][nt].x = pk2(acc[0], acc[1]);
                qk[mt][nt].y = pk2(acc[2], acc[3]);
            } else {                 // V head mt-4 -> LDS [64 m][16 d]
                int tok = 16*nt + ln;
                uint2 u; u.x = pk2(acc[0], acc[1]); u.y = pk2(acc[2], acc[3]);
                *(uint2*)(smem + (mt-4)*2048 + tok*32 + 8*g) = u;
            }
        }
    }

    const uint32_t one2 = 0x3f803f80u;          // bf16 1.0 pair
    const bf16x8 ones = mk8q(one2, one2, one2, one2);

    // ---- per-head attention; per-nt pipeline ----
    #pragma unroll
    for (int h = 0; h < 2; ++h) {
        // V B-frags via hw transpose read
        uint32_t va = Lb + h*2048 + 256*g + 8*ln;
        uint2 v00 = tr16<0>(va),    v01 = tr16<128>(va);
        uint2 v10 = tr16<1024>(va), v11 = tr16<1152>(va);
        lgkm0();
        bf16x8 vb0 = mk8u(v00, v01), vb1 = mk8u(v10, v11);

        f32x4 bpc[4];
        #pragma unroll
        for (int mt = 0; mt < 4; ++mt)
            bpc[mt] = biasF[((h*4 + 0)*4 + mt)*64 + lane];

        #pragma unroll
        for (int nt = 0; nt < 4; ++nt) {
            // prefetch next nt's bias while computing
            f32x4 bpn[4];
            const int ntn = (nt < 3) ? nt + 1 : 3;
            #pragma unroll
            for (int mt = 0; mt < 4; ++mt)
                bpn[mt] = biasF[((h*4 + ntn)*4 + mt)*64 + lane];

            // S^T tiles (k=16 exact): A=K frag, B=Q frag, C=bias (f32 direct)
            __builtin_amdgcn_s_setprio(1);
            f32x4 sc[4];
            #pragma unroll
            for (int mt = 0; mt < 4; ++mt)
                sc[mt] = mfma16(qk[2+h][mt], qk[h][nt], bpc[mt]);
            __builtin_amdgcn_s_setprio(0);

            // exp2 (raw v_exp_f32; inputs bounded, no libm expansion)
            #pragma unroll
            for (int mt = 0; mt < 4; ++mt) {
                sc[mt][0]=__builtin_amdgcn_exp2f(sc[mt][0]);
                sc[mt][1]=__builtin_amdgcn_exp2f(sc[mt][1]);
                sc[mt][2]=__builtin_amdgcn_exp2f(sc[mt][2]);
                sc[mt][3]=__builtin_amdgcn_exp2f(sc[mt][3]);
            }

            // pack P UNNORMALIZED and redistribute to PV A-frags in-register
            uint32_t pkA[4], pkB[4];
            #pragma unroll
            for (int mt = 0; mt < 4; ++mt) {
                pkA[mt] = pk2(sc[mt][0], sc[mt][1]);
                pkB[mt] = pk2(sc[mt][2], sc[mt][3]);
            }
            uint32_t a0 = pkA[0], a1 = pkA[1]; pl32(a0, a1); pl16(a0, a1);
            uint32_t b0 = pkB[0], b1 = pkB[1]; pl32(b0, b1); pl16(b0, b1);
            bf16x8 pa0 = mk8q(a0, b0, a1, b1);
            uint32_t a2 = pkA[2], a3 = pkA[3]; pl32(a2, a3); pl16(a2, a3);
            uint32_t b2 = pkB[2], b3 = pkB[3]; pl32(b2, b3); pl16(b2, b3);
            bf16x8 pa1 = mk8q(a2, b2, a3, b3);

            // PV (k=32 over m) + row-sum via ones-MFMA (same D row layout as oc)
            __builtin_amdgcn_s_setprio(1);
            f32x4 z = {0.f,0.f,0.f,0.f};
            z = __builtin_amdgcn_mfma_f32_16x16x32_bf16(pa0, vb0, z, 0, 0, 0);
            f32x4 oc = __builtin_amdgcn_mfma_f32_16x16x32_bf16(pa1, vb1, z, 0, 0, 0);
            f32x4 sm = {0.f,0.f,0.f,0.f};
            sm = __builtin_amdgcn_mfma_f32_16x16x32_bf16(pa0, ones, sm, 0, 0, 0);
            sm = __builtin_amdgcn_mfma_f32_16x16x32_bf16(pa1, ones, sm, 0, 0, 0);
            __builtin_amdgcn_s_setprio(0);

            // normalize post-PV (raw v_rcp_f32)
            oc[0] *= __builtin_amdgcn_rcpf(sm[0]);
            oc[1] *= __builtin_amdgcn_rcpf(sm[1]);
            oc[2] *= __builtin_amdgcn_rcpf(sm[2]);
            oc[3] *= __builtin_amdgcn_rcpf(sm[3]);

            // O^T store overlaying V half h (dead after tr16 above)
            uint2 u; u.x = pk2(oc[0], oc[1]); u.y = pk2(oc[2], oc[3]);
            *(uint2*)(smem + h*2048 + (nt*4 + (ln>>2))*128 + (ln&3)*32 + 8*g) = u;

            #pragma unroll
            for (int mt = 0; mt < 4; ++mt) bpc[mt] = bpn[mt];
        }
    }

    // ---- proj (swapped): out^T = mfma(W2, O^T) ----
    const uint16_t* pwbf = (const uint16_t*)(wsc + WS_PROJW);
    bf16x8 w2f[2];
    w2f[0] = *(const bf16x8*)(pwbf + ln*32 + 8*g);
    w2f[1] = *(const bf16x8*)(pwbf + (16 + ln)*32 + 8*g);
    float4 pbv[2];
    pbv[0] = *(const float4*)(proj_b + 4*g);
    pbv[1] = *(const float4*)(proj_b + 16 + 4*g);

    uint32_t ob = Lb + ((uint32_t)(g >> 1) << 11) + ((uint32_t)(g & 1) << 8) + 8*ln;
    uint2 a0=tr16<0>(ob),    a1=tr16<128>(ob);
    uint2 b0=tr16<512>(ob),  b1=tr16<640>(ob);
    uint2 c0=tr16<1024>(ob), c1=tr16<1152>(ob);
    uint2 d0=tr16<1536>(ob), d1=tr16<1664>(ob);
    lgkm0();
    bf16x8 oa[4];
    oa[0]=mk8u(a0,a1); oa[1]=mk8u(b0,b1); oa[2]=mk8u(c0,c1); oa[3]=mk8u(d0,d1);

    #pragma unroll
    for (int mt2 = 0; mt2 < 2; ++mt2) {
        #pragma unroll
        for (int nt = 0; nt < 4; ++nt) {
            f32x4 acc = {pbv[mt2].x, pbv[mt2].y, pbv[mt2].z, pbv[mt2].w};
            acc = __builtin_amdgcn_mfma_f32_16x16x32_bf16(w2f[mt2], oa[nt], acc, 0, 0, 0);
            if (WSPATH) {   // wout[win][l=16nt+ln][co=16mt2+4g+0..3], packed
                uint2 u; u.x = pk2(acc[0], acc[1]); u.y = pk2(acc[2], acc[3]);
                *(uint2*)(wout + ((size_t)wid*64 + 16*nt + ln)*32 + 16*mt2 + 4*g) = u;
            } else {
                #pragma unroll
                for (int r = 0; r < 4; ++r)
                    atomicAdd(out + (size_t)pixb[nt]*32 + 16*mt2 + 4*g + r, acc[r]);
            }
        }
    }
}

// gather <=3x3 contributing windows per output pixel, divide by count.
// Block index remapped so block b serves FRAME (b&7) and lands on XCD (b&7) —
// the same XCD whose L2 holds that frame's wout slice (win_attn swizzle). Bijective.
__global__ __launch_bounds__(256) void gather_out(const uint16_t* __restrict__ ws,
                                                  float* __restrict__ out)
{
    const int b = blockIdx.x;
    int gid = ((b & 7) << 17) + ((b >> 3) << 8) + threadIdx.x;   // pixels * 8 float4s
    int q = gid & 7;
    int c = (gid >> 3) & 127;
    int r = (gid >> 10) & 127;
    int t = gid >> 17;

    int wr[3], pr[3], nr = 0;
    { int w0 = r >> 2;
      wr[0] = w0; pr[0] = r & 3; nr = 1;
      if (w0 >= 1) { wr[nr] = w0 - 1; pr[nr] = (r & 3) + 4; nr++; }
      if (r >= 123 && r <= 126) { wr[nr] = 31; pr[nr] = 130 - r; nr++; } }
    int wc[3], pc[3], nc = 0;
    { int w0 = c >> 2;
      wc[0] = w0; pc[0] = c & 3; nc = 1;
      if (w0 >= 1) { wc[nc] = w0 - 1; pc[nc] = (c & 3) + 4; nc++; }
      if (c >= 123 && c <= 126) { wc[nc] = 31; pc[nc] = 130 - c; nc++; } }

    float4 acc; acc.x = acc.y = acc.z = acc.w = 0.f;
    #pragma unroll
    for (int i = 0; i < 3; ++i) {
        #pragma unroll
        for (int j = 0; j < 3; ++j) {
            if (i < nr && j < nc) {
                int win = t*1024 + wr[i]*32 + wc[j];
                int tok = pr[i]*8 + pc[j];
                ushort4 v = *reinterpret_cast<const ushort4*>(ws + ((size_t)win*64 + tok)*32 + q*4);
                union { uint32_t u; float f; } a0,a1,a2,a3;
                a0.u = (uint32_t)v.x << 16; a1.u = (uint32_t)v.y << 16;
                a2.u = (uint32_t)v.z << 16; a3.u = (uint32_t)v.w << 16;
                acc.x += a0.f; acc.y += a1.f; acc.z += a2.f; acc.w += a3.f;
            }
        }
    }
    float inv = __builtin_amdgcn_rcpf((float)(nr*nc));
    acc.x *= inv; acc.y *= inv; acc.z *= inv; acc.w *= inv;
    reinterpret_cast<float4*>(out)[gid] = acc;
}

// fallback normalize (atomic path)
__global__ __launch_bounds__(256) void div_kernel(float* __restrict__ out)
{
    int gid = blockIdx.x*blockDim.x + threadIdx.x;
    const int total4 = 8*128*128*32/4;
    if (gid >= total4) return;
    int pix = gid >> 3;
    int c_ = pix % 128;
    int r_ = (pix / 128) % 128;
    int cr = 0, cc = 0;
    for (int i = 0; i < 32; ++i) {
        #pragma unroll
        for (int p = 0; p < 8; ++p) {
            int rr = i*4 + p; if (rr >= 128) rr = 254 - rr;
            cr += (rr == r_);
            int aa = i*4 + p; if (aa >= 128) aa = 254 - aa;
            cc += (aa == c_);
        }
    }
    float inv = 1.f / ((float)cr*(float)cc + 1e-10f);
    float4* p4 = reinterpret_cast<float4*>(out) + gid;
    float4 v = *p4;
    v.x *= inv; v.y *= inv; v.z *= inv; v.w *= inv;
    *p4 = v;
}

extern "C" void kernel_launch(void* const* d_in, const int* in_sizes, int n_in,
                              void* d_out, int out_size, void* d_ws, size_t ws_size,
                              hipStream_t stream) {
    const float* x       = (const float*)d_in[0];
    const float* qkv_w   = (const float*)d_in[1];
    const float* qkv_b   = (const float*)d_in[2];
    const float* rel_tab = (const float*)d_in[3];
    const float* proj_w  = (const float*)d_in[4];
    const float* proj_b  = (const float*)d_in[5];
    float* out = (float*)d_out;
    char* ws = (char*)d_ws;

    prep<<<16, 256, 0, stream>>>(qkv_w, qkv_b, rel_tab, proj_w, ws);

    if (ws_size >= NEED_FULL) {
        win_attn<1><<<4096, 128, 0, stream>>>(x, proj_b, (const char*)ws,
                                              (uint16_t*)(ws + WS_OUT), out);
        gather_out<<<4096, 256, 0, stream>>>((const uint16_t*)(ws + WS_OUT), out);
    } else {
        hipMemsetAsync(out, 0, (size_t)out_size*sizeof(float), stream);
        win_attn<0><<<4096, 128, 0, stream>>>(x, proj_b, (const char*)ws, nullptr, out);
        const int tot4 = 8*128*128*32/4;
        div_kernel<<<(tot4 + 255)/256, 256, 0, stream>>>(out);
    }
}